// Round 1
// baseline (16571.423 us; speedup 1.0000x reference)
//
#include <hip/hip_runtime.h>

typedef _Float16 f16;
typedef _Float16 h2 __attribute__((ext_vector_type(2)));
typedef _Float16 h8 __attribute__((ext_vector_type(8)));
typedef float f4 __attribute__((ext_vector_type(4)));

constexpr int Bb = 64, Tt = 2048, Xx = 128, Hh = 256, G4 = 1024, Z2 = 128;

__device__ __forceinline__ float fdot2f(h2 a, h2 b, float c) {
#if __has_builtin(__builtin_amdgcn_fdot2)
  return __builtin_amdgcn_fdot2(a, b, c, false);
#else
  return c + (float)a[0] * (float)b[0] + (float)a[1] * (float)b[1];
#endif
}
__device__ __forceinline__ float sigmf(float x) {
  float e = __expf(-x);
  return __builtin_amdgcn_rcpf(1.0f + e);
}
__device__ __forceinline__ float tanhf_(float x) {
  float e = __expf(2.0f * x);
  return 1.0f - 2.0f * __builtin_amdgcn_rcpf(e + 1.0f);
}
__device__ __forceinline__ h2 bch2(unsigned int u) { return __builtin_bit_cast(h2, u); }

// ---------------- casts ----------------
__global__ void cast_f16_k(const float* __restrict__ in, f16* __restrict__ out, int n) {
  int i = (blockIdx.x * 256 + threadIdx.x) * 4;
  if (i >= n) return;
  float4 v = *(const float4*)(in + i);
  h2 a = {(f16)v.x, (f16)v.y};
  h2 b = {(f16)v.z, (f16)v.w};
  uint2 o = {__builtin_bit_cast(unsigned int, a), __builtin_bit_cast(unsigned int, b)};
  *(uint2*)(out + i) = o;
}

// Wh (H=256, 4H=1024) fp32 -> WhT (1024, 256) f16, writes coalesced
__global__ void cast_whT_k(const float* __restrict__ Wh, f16* __restrict__ WhT) {
  int idx = blockIdx.x * 256 + threadIdx.x;  // 262144 = G4*Hh, WhT-linear
  int g = idx >> 8, k = idx & 255;
  WhT[idx] = (f16)Wh[(long)k * G4 + g];
}

// ---------------- generic f16 MFMA GEMM, 64x64 tile ----------------
// A: (M x K) f16 with row remap: arow = (m>>a_shift)*a_ostride + a_t0 + (m & ((1<<a_shift)-1))
// Bm: (K x N) f16 row-major. bias: fp32[N].
// mode 0: C16 = acc+bias (f16);  mode 1: C16 = relu(acc+bias) (f16);
// mode 2: fp32 split-out: col<64 -> Cmu, col>=64 -> Cls, with (b,t) row remap.
__global__ __launch_bounds__(256, 4) void gemm_f16_k(
    const f16* __restrict__ A, const f16* __restrict__ Bm, const float* __restrict__ bias,
    f16* __restrict__ C16, float* __restrict__ Cmu, float* __restrict__ Cls,
    int N, int K, int a_shift, int a_ostride, int a_t0,
    int mode, int o_t0, int tcshift)
{
  __shared__ __align__(16) f16 At[64][48];
  __shared__ __align__(16) f16 Bt[64][48];
  const int tid = threadIdx.x;
  const int mblk = blockIdx.x, nblk = blockIdx.y;
  const int w = tid >> 6, lane = tid & 63;

  // A staging: thread -> one 16B chunk (8 halfs)
  const int sa_row = tid >> 2, sa_k = (tid & 3) * 8;
  const int m_g = mblk * 64 + sa_row;
  const long arow = (long)(m_g >> a_shift) * a_ostride + a_t0 + (m_g & ((1 << a_shift) - 1));
  const f16* aptr = A + arow * K + sa_k;
  // B staging: thread -> 8 halfs along n, then transpose into Bt[col][k]
  const int sb_k = tid >> 3, sb_n = (tid & 7) * 8;
  const f16* bptr = Bm + (long)sb_k * N + nblk * 64 + sb_n;

  f4 acc[4];
#pragma unroll
  for (int i = 0; i < 4; ++i) acc[i] = (f4){0.f, 0.f, 0.f, 0.f};

  const int arow_l = w * 16 + (lane & 15);
  const int k0 = (lane >> 4) * 8;

  for (int kk = 0; kk < K; kk += 32) {
    uint4 av = *(const uint4*)(aptr + kk);
    uint4 bv = *(const uint4*)(bptr + (long)kk * N);
    __syncthreads();
    *(uint4*)&At[sa_row][sa_k] = av;
    h8 bx = __builtin_bit_cast(h8, bv);
#pragma unroll
    for (int j = 0; j < 8; ++j) Bt[sb_n + j][sb_k] = bx[j];
    __syncthreads();
    h8 af = *(const h8*)&At[arow_l][k0];
#pragma unroll
    for (int nt = 0; nt < 4; ++nt) {
      h8 bf = *(const h8*)&Bt[nt * 16 + (lane & 15)][k0];
      acc[nt] = __builtin_amdgcn_mfma_f32_16x16x32_f16(af, bf, acc[nt], 0, 0, 0);
    }
  }

  const int row_l = w * 16 + ((lane >> 4) << 2);
  const int col_l = lane & 15;
#pragma unroll
  for (int nt = 0; nt < 4; ++nt) {
    int gcol = nblk * 64 + nt * 16 + col_l;
    float bv = bias[gcol];
#pragma unroll
    for (int r = 0; r < 4; ++r) {
      int gm = mblk * 64 + row_l + r;
      float val = acc[nt][r] + bv;
      if (mode == 1) val = fmaxf(val, 0.f);
      if (mode <= 1) {
        C16[(long)gm * N + gcol] = (f16)val;
      } else {
        int bb = gm >> tcshift, tl = gm & ((1 << tcshift) - 1);
        long orow = (long)bb * Tt + o_t0 + tl;
        if (gcol < 64) Cmu[orow * 64 + gcol] = val;
        else Cls[orow * 64 + (gcol - 64)] = val;
      }
    }
  }
}

// ---------------- persistent-weight LSTM scan ----------------
// One workgroup (512 thr) per batch element. Thread tid owns gate columns
// g0=tid, g1=tid+512 of the 1024 [i|f|g|o] gates.
//   tid<256  : (i_j, g_j) for h-column j=tid
//   tid>=256 : (f_j, o_j) + cell state c_j for j=tid-256
// Wh^T f16: k<208 in registers (104 h2 per column), k in [208,256) in LDS.
__global__ __launch_bounds__(512, 2) void lstm_rec_k(
    const f16* __restrict__ WhT, const f16* __restrict__ xp,
    f16* __restrict__ hout, float* __restrict__ c_state, f16* __restrict__ h_state,
    int TC, int first)
{
  const int b = blockIdx.x, tid = threadIdx.x;
  const int g0 = tid, g1 = tid + 512;
  __shared__ __align__(16) h2 hbuf[128];    // h_t as 128 f16 pairs
  __shared__ float pbuf[256];               // sigmoid(i)*tanh(g)
  __shared__ h2 wlds[12][1024][2];          // weight tail, k-major: 96 KB

  h2 w0[104], w1[104];
  {
    const uint4* p0 = (const uint4*)(WhT + (long)g0 * Hh);
    const uint4* p1 = (const uint4*)(WhT + (long)g1 * Hh);
#pragma unroll
    for (int i = 0; i < 26; ++i) {
      uint4 v = p0[i];
      w0[4 * i + 0] = bch2(v.x); w0[4 * i + 1] = bch2(v.y);
      w0[4 * i + 2] = bch2(v.z); w0[4 * i + 3] = bch2(v.w);
    }
#pragma unroll
    for (int i = 0; i < 26; ++i) {
      uint4 v = p1[i];
      w1[4 * i + 0] = bch2(v.x); w1[4 * i + 1] = bch2(v.y);
      w1[4 * i + 2] = bch2(v.z); w1[4 * i + 3] = bch2(v.w);
    }
    const h2* r0 = (const h2*)(WhT + (long)g0 * Hh);
    const h2* r1 = (const h2*)(WhT + (long)g1 * Hh);
#pragma unroll
    for (int jp = 0; jp < 12; ++jp) {
      wlds[jp][g0][0] = r0[104 + 2 * jp]; wlds[jp][g0][1] = r0[105 + 2 * jp];
      wlds[jp][g1][0] = r1[104 + 2 * jp]; wlds[jp][g1][1] = r1[105 + 2 * jp];
    }
  }

  float c = 0.f;
  if (tid >= 256 && !first) c = c_state[b * Hh + (tid - 256)];
  if (tid < 128) {
    h2 hz = {(f16)0.f, (f16)0.f};
    hbuf[tid] = first ? hz : ((const h2*)h_state)[b * 128 + tid];
  }
  __syncthreads();

  const f16* xprow = xp + (long)b * TC * G4;
  f16 xc0 = xprow[g0], xc1 = xprow[g1];
  for (int t = 0; t < TC; ++t) {
    int tn = (t + 1 < TC) ? t + 1 : t;
    f16 xn0 = xprow[(long)tn * G4 + g0];   // prefetch next step's x-projection
    f16 xn1 = xprow[(long)tn * G4 + g1];

    float acc0 = (float)xc0, acc1 = (float)xc1;   // bh folded into xp already
    const uint4* hb4 = (const uint4*)hbuf;
#pragma unroll
    for (int i = 0; i < 26; ++i) {
      uint4 hv = hb4[i];
      h2 p0 = bch2(hv.x), p1 = bch2(hv.y), p2 = bch2(hv.z), p3 = bch2(hv.w);
      acc0 = fdot2f(w0[4 * i + 0], p0, acc0); acc1 = fdot2f(w1[4 * i + 0], p0, acc1);
      acc0 = fdot2f(w0[4 * i + 1], p1, acc0); acc1 = fdot2f(w1[4 * i + 1], p1, acc1);
      acc0 = fdot2f(w0[4 * i + 2], p2, acc0); acc1 = fdot2f(w1[4 * i + 2], p2, acc1);
      acc0 = fdot2f(w0[4 * i + 3], p3, acc0); acc1 = fdot2f(w1[4 * i + 3], p3, acc1);
    }
#pragma unroll
    for (int jp = 0; jp < 12; ++jp) {
      uint2 wa = *(const uint2*)&wlds[jp][g0][0];
      uint2 wb = *(const uint2*)&wlds[jp][g1][0];
      h2 ha = hbuf[104 + 2 * jp], hb = hbuf[105 + 2 * jp];
      acc0 = fdot2f(bch2(wa.x), ha, acc0); acc0 = fdot2f(bch2(wa.y), hb, acc0);
      acc1 = fdot2f(bch2(wb.x), ha, acc1); acc1 = fdot2f(bch2(wb.y), hb, acc1);
    }

    float pa, pb_ = 0.f;
    if (tid < 256) {
      pa = sigmf(acc0) * tanhf_(acc1);   // sig(i)*tanh(g)
      pbuf[tid] = pa;
    } else {
      pa = sigmf(acc0);                  // sig(f)
      pb_ = sigmf(acc1);                 // sig(o)
    }
    __syncthreads();
    if (tid >= 256) {
      int j = tid - 256;
      c = pa * c + pbuf[j];
      float hval = pb_ * tanhf_(c);
      f16 hh = (f16)hval;
      ((f16*)hbuf)[j] = hh;
      hout[((long)b * TC + t) * Hh + j] = hh;
    }
    __syncthreads();
    xc0 = xn0; xc1 = xn1;
  }
  if (tid >= 256) c_state[b * Hh + (tid - 256)] = c;
  if (tid < 128) ((h2*)h_state)[b * 128 + tid] = hbuf[tid];
}

// ---------------- host ----------------
extern "C" void kernel_launch(void* const* d_in, const int* in_sizes, int n_in,
                              void* d_out, int out_size, void* d_ws, size_t ws_size,
                              hipStream_t stream)
{
  const float* x  = (const float*)d_in[0];
  const float* Wi = (const float*)d_in[1];
  const float* Wh = (const float*)d_in[2];
  const float* bh = (const float*)d_in[3];
  const float* W1 = (const float*)d_in[4];
  const float* b1 = (const float*)d_in[5];
  const float* W2 = (const float*)d_in[6];
  const float* b2 = (const float*)d_in[7];
  float* out = (float*)d_out;

  char* ws = (char*)d_ws;
  size_t off = 0;
  auto alloc = [&](size_t bytes) -> char* {
    char* p = ws + off;
    off = (off + bytes + 255) & ~(size_t)255;
    return p;
  };
  f16* x16   = (f16*)alloc((size_t)Bb * Tt * Xx * 2);
  f16* wi16  = (f16*)alloc((size_t)Xx * G4 * 2);
  f16* whT16 = (f16*)alloc((size_t)G4 * Hh * 2);
  f16* w116  = (f16*)alloc((size_t)Hh * Hh * 2);
  f16* w216  = (f16*)alloc((size_t)Hh * Z2 * 2);
  float* cst = (float*)alloc((size_t)Bb * Hh * 4);
  f16* hst   = (f16*)alloc((size_t)Bb * Hh * 2);

  int tc = 2048;
  while (tc > 32) {
    size_t need = (size_t)Bb * tc * G4 * 2 + (size_t)Bb * tc * Hh * 2;
    if (off + need <= ws_size) break;
    tc >>= 1;
  }
  int tcsh = __builtin_ctz((unsigned)tc);
  f16* xp16 = (f16*)alloc((size_t)Bb * tc * G4 * 2);
  f16* h16  = (f16*)alloc((size_t)Bb * tc * Hh * 2);
  f16* hid16 = xp16;  // head hidden aliases xp (xp fully consumed by the scan)

  cast_f16_k<<<(Bb * Tt * Xx) / 1024, 256, 0, stream>>>(x, x16, Bb * Tt * Xx);
  cast_f16_k<<<(Xx * G4) / 1024, 256, 0, stream>>>(Wi, wi16, Xx * G4);
  cast_f16_k<<<(Hh * Hh) / 1024, 256, 0, stream>>>(W1, w116, Hh * Hh);
  cast_f16_k<<<(Hh * Z2) / 1024, 256, 0, stream>>>(W2, w216, Hh * Z2);
  cast_whT_k<<<(Hh * G4) / 256, 256, 0, stream>>>(Wh, whT16);

  float* mu = out;
  float* ls = out + (size_t)Bb * Tt * 64;

  for (int t0 = 0; t0 < Tt; t0 += tc) {
    dim3 gx(Bb * tc / 64, G4 / 64);
    gemm_f16_k<<<gx, 256, 0, stream>>>(x16, wi16, bh, xp16, nullptr, nullptr,
                                       G4, Xx, tcsh, Tt, t0, 0, 0, 0);
    lstm_rec_k<<<Bb, 512, 0, stream>>>(whT16, xp16, h16, cst, hst, tc, (t0 == 0) ? 1 : 0);
    dim3 g1g(Bb * tc / 64, Hh / 64);
    gemm_f16_k<<<g1g, 256, 0, stream>>>(h16, w116, b1, hid16, nullptr, nullptr,
                                        Hh, Hh, 30, 0, 0, 1, 0, 0);
    dim3 g2g(Bb * tc / 64, Z2 / 64);
    gemm_f16_k<<<g2g, 256, 0, stream>>>(hid16, w216, b2, nullptr, mu, ls,
                                        Z2, Hh, 30, 0, 0, 2, t0, tcsh);
  }
}

// Round 2
// 15998.579 us; speedup vs baseline: 1.0358x; 1.0358x over previous
//
#include <hip/hip_runtime.h>

typedef _Float16 f16;
typedef _Float16 h2 __attribute__((ext_vector_type(2)));
typedef _Float16 h8 __attribute__((ext_vector_type(8)));
typedef float f4 __attribute__((ext_vector_type(4)));

constexpr int Bb = 64, Tt = 2048, Xx = 128, Hh = 256, G4 = 1024, Z2 = 128;

__device__ __forceinline__ float fdot2f(h2 a, h2 b, float c) {
#if __has_builtin(__builtin_amdgcn_fdot2)
  return __builtin_amdgcn_fdot2(a, b, c, false);
#else
  return c + (float)a[0] * (float)b[0] + (float)a[1] * (float)b[1];
#endif
}
__device__ __forceinline__ float sigmf(float x) {
  float e = __expf(-x);
  return __builtin_amdgcn_rcpf(1.0f + e);
}
__device__ __forceinline__ float tanhf_(float x) {
  float e = __expf(2.0f * x);
  return 1.0f - 2.0f * __builtin_amdgcn_rcpf(e + 1.0f);
}
__device__ __forceinline__ h2 bch2(unsigned int u) { return __builtin_bit_cast(h2, u); }

// ---------------- casts ----------------
__global__ void cast_f16_k(const float* __restrict__ in, f16* __restrict__ out, int n) {
  int i = (blockIdx.x * 256 + threadIdx.x) * 4;
  if (i >= n) return;
  float4 v = *(const float4*)(in + i);
  h2 a = {(f16)v.x, (f16)v.y};
  h2 b = {(f16)v.z, (f16)v.w};
  uint2 o = {__builtin_bit_cast(unsigned int, a), __builtin_bit_cast(unsigned int, b)};
  *(uint2*)(out + i) = o;
}

// Wh (H=256, 4H=1024) fp32 -> WhT (1024, 256) f16, writes coalesced
__global__ void cast_whT_k(const float* __restrict__ Wh, f16* __restrict__ WhT) {
  int idx = blockIdx.x * 256 + threadIdx.x;  // 262144 = G4*Hh, WhT-linear
  int g = idx >> 8, k = idx & 255;
  WhT[idx] = (f16)Wh[(long)k * G4 + g];
}

// ---------------- generic f16 MFMA GEMM, 64x64 tile ----------------
__global__ __launch_bounds__(256, 4) void gemm_f16_k(
    const f16* __restrict__ A, const f16* __restrict__ Bm, const float* __restrict__ bias,
    f16* __restrict__ C16, float* __restrict__ Cmu, float* __restrict__ Cls,
    int N, int K, int a_shift, int a_ostride, int a_t0,
    int mode, int o_t0, int tcshift)
{
  __shared__ __align__(16) f16 At[64][48];
  __shared__ __align__(16) f16 Bt[64][48];
  const int tid = threadIdx.x;
  const int mblk = blockIdx.x, nblk = blockIdx.y;
  const int w = tid >> 6, lane = tid & 63;

  const int sa_row = tid >> 2, sa_k = (tid & 3) * 8;
  const int m_g = mblk * 64 + sa_row;
  const long arow = (long)(m_g >> a_shift) * a_ostride + a_t0 + (m_g & ((1 << a_shift) - 1));
  const f16* aptr = A + arow * K + sa_k;
  const int sb_k = tid >> 3, sb_n = (tid & 7) * 8;
  const f16* bptr = Bm + (long)sb_k * N + nblk * 64 + sb_n;

  f4 acc[4];
#pragma unroll
  for (int i = 0; i < 4; ++i) acc[i] = (f4){0.f, 0.f, 0.f, 0.f};

  const int arow_l = w * 16 + (lane & 15);
  const int k0 = (lane >> 4) * 8;

  for (int kk = 0; kk < K; kk += 32) {
    uint4 av = *(const uint4*)(aptr + kk);
    uint4 bv = *(const uint4*)(bptr + (long)kk * N);
    __syncthreads();
    *(uint4*)&At[sa_row][sa_k] = av;
    h8 bx = __builtin_bit_cast(h8, bv);
#pragma unroll
    for (int j = 0; j < 8; ++j) Bt[sb_n + j][sb_k] = bx[j];
    __syncthreads();
    h8 af = *(const h8*)&At[arow_l][k0];
#pragma unroll
    for (int nt = 0; nt < 4; ++nt) {
      h8 bf = *(const h8*)&Bt[nt * 16 + (lane & 15)][k0];
      acc[nt] = __builtin_amdgcn_mfma_f32_16x16x32_f16(af, bf, acc[nt], 0, 0, 0);
    }
  }

  const int row_l = w * 16 + ((lane >> 4) << 2);
  const int col_l = lane & 15;
#pragma unroll
  for (int nt = 0; nt < 4; ++nt) {
    int gcol = nblk * 64 + nt * 16 + col_l;
    float bv = bias[gcol];
#pragma unroll
    for (int r = 0; r < 4; ++r) {
      int gm = mblk * 64 + row_l + r;
      float val = acc[nt][r] + bv;
      if (mode == 1) val = fmaxf(val, 0.f);
      if (mode <= 1) {
        C16[(long)gm * N + gcol] = (f16)val;
      } else {
        int bb = gm >> tcshift, tl = gm & ((1 << tcshift) - 1);
        long orow = (long)bb * Tt + o_t0 + tl;
        if (gcol < 64) Cmu[orow * 64 + gcol] = val;
        else Cls[orow * 64 + (gcol - 64)] = val;
      }
    }
  }
}

// ---------------- persistent-weight LSTM scan ----------------
// One workgroup (512 thr) per batch element, pinned to 2 waves/EU so the
// allocator has the full 256-VGPR budget (round-1: default heuristic targeted
// 4 waves/EU -> VGPR_Count=128 -> weight arrays spilled -> 8 us/step).
// Thread tid owns gate columns g0=tid, g1=tid+512 of 1024 [i|f|g|o] gates.
//   tid<256  : (i_j, g_j) for h-column j=tid
//   tid>=256 : (f_j, o_j) + cell state c_j for j=tid-256
// Wh^T f16: k<192 in registers (96 h2 per column = 192 VGPRs), k in [192,256)
// in LDS (128 KB, layout [jp][col][2] -> 2-way bank access = free).
__global__ void __launch_bounds__(512) __attribute__((amdgpu_waves_per_eu(2, 2)))
lstm_rec_k(
    const f16* __restrict__ WhT, const f16* __restrict__ xp,
    f16* __restrict__ hout, float* __restrict__ c_state, f16* __restrict__ h_state,
    int TC, int first)
{
  const int b = blockIdx.x, tid = threadIdx.x;
  const int g0 = tid, g1 = tid + 512;
  __shared__ __align__(16) h2 hbuf[128];    // h_t as 128 f16 pairs
  __shared__ float pbuf[256];               // sigmoid(i)*tanh(g)
  __shared__ h2 wlds[16][1024][2];          // weight tail k in [192,256): 128 KB

  h2 w0[96], w1[96];
  {
    const h2* p0 = (const h2*)(WhT + (long)g0 * Hh);
    const h2* p1 = (const h2*)(WhT + (long)g1 * Hh);
#pragma unroll
    for (int i = 0; i < 96; ++i) w0[i] = p0[i];
#pragma unroll
    for (int i = 0; i < 96; ++i) w1[i] = p1[i];
#pragma unroll
    for (int jp = 0; jp < 16; ++jp) {
      wlds[jp][g0][0] = p0[96 + 2 * jp]; wlds[jp][g0][1] = p0[97 + 2 * jp];
      wlds[jp][g1][0] = p1[96 + 2 * jp]; wlds[jp][g1][1] = p1[97 + 2 * jp];
    }
  }

  float c = 0.f;
  if (tid >= 256 && !first) c = c_state[b * Hh + (tid - 256)];
  if (tid < 128) {
    h2 hz = {(f16)0.f, (f16)0.f};
    hbuf[tid] = first ? hz : ((const h2*)h_state)[b * 128 + tid];
  }
  __syncthreads();

  const f16* xprow = xp + (long)b * TC * G4;
  f16 xc0 = xprow[g0], xc1 = xprow[g1];
  for (int t = 0; t < TC; ++t) {
    int tn = (t + 1 < TC) ? t + 1 : t;
    f16 xn0 = xprow[(long)tn * G4 + g0];   // prefetch next step's x-projection
    f16 xn1 = xprow[(long)tn * G4 + g1];

    float acc0 = (float)xc0, acc1 = (float)xc1;   // bh folded into xp already
    const uint4* hb4 = (const uint4*)hbuf;
#pragma unroll
    for (int i = 0; i < 24; ++i) {
      uint4 hv = hb4[i];
      h2 p0 = bch2(hv.x), p1 = bch2(hv.y), p2 = bch2(hv.z), p3 = bch2(hv.w);
      acc0 = fdot2f(w0[4 * i + 0], p0, acc0); acc1 = fdot2f(w1[4 * i + 0], p0, acc1);
      acc0 = fdot2f(w0[4 * i + 1], p1, acc0); acc1 = fdot2f(w1[4 * i + 1], p1, acc1);
      acc0 = fdot2f(w0[4 * i + 2], p2, acc0); acc1 = fdot2f(w1[4 * i + 2], p2, acc1);
      acc0 = fdot2f(w0[4 * i + 3], p3, acc0); acc1 = fdot2f(w1[4 * i + 3], p3, acc1);
    }
#pragma unroll
    for (int jp = 0; jp < 16; ++jp) {
      uint2 wa = *(const uint2*)&wlds[jp][g0][0];
      uint2 wb = *(const uint2*)&wlds[jp][g1][0];
      h2 ha = hbuf[96 + 2 * jp], hb = hbuf[97 + 2 * jp];
      acc0 = fdot2f(bch2(wa.x), ha, acc0); acc0 = fdot2f(bch2(wa.y), hb, acc0);
      acc1 = fdot2f(bch2(wb.x), ha, acc1); acc1 = fdot2f(bch2(wb.y), hb, acc1);
    }

    float pa, pb_ = 0.f;
    if (tid < 256) {
      pa = sigmf(acc0) * tanhf_(acc1);   // sig(i)*tanh(g)
      pbuf[tid] = pa;
    } else {
      pa = sigmf(acc0);                  // sig(f)
      pb_ = sigmf(acc1);                 // sig(o)
    }
    __syncthreads();
    if (tid >= 256) {
      int j = tid - 256;
      c = pa * c + pbuf[j];
      float hval = pb_ * tanhf_(c);
      f16 hh = (f16)hval;
      ((f16*)hbuf)[j] = hh;
      hout[((long)b * TC + t) * Hh + j] = hh;
    }
    __syncthreads();
    xc0 = xn0; xc1 = xn1;
  }
  if (tid >= 256) c_state[b * Hh + (tid - 256)] = c;
  if (tid < 128) ((h2*)h_state)[b * 128 + tid] = hbuf[tid];
}

// ---------------- host ----------------
extern "C" void kernel_launch(void* const* d_in, const int* in_sizes, int n_in,
                              void* d_out, int out_size, void* d_ws, size_t ws_size,
                              hipStream_t stream)
{
  const float* x  = (const float*)d_in[0];
  const float* Wi = (const float*)d_in[1];
  const float* Wh = (const float*)d_in[2];
  const float* bh = (const float*)d_in[3];
  const float* W1 = (const float*)d_in[4];
  const float* b1 = (const float*)d_in[5];
  const float* W2 = (const float*)d_in[6];
  const float* b2 = (const float*)d_in[7];
  float* out = (float*)d_out;

  char* ws = (char*)d_ws;
  size_t off = 0;
  auto alloc = [&](size_t bytes) -> char* {
    char* p = ws + off;
    off = (off + bytes + 255) & ~(size_t)255;
    return p;
  };
  f16* x16   = (f16*)alloc((size_t)Bb * Tt * Xx * 2);
  f16* wi16  = (f16*)alloc((size_t)Xx * G4 * 2);
  f16* whT16 = (f16*)alloc((size_t)G4 * Hh * 2);
  f16* w116  = (f16*)alloc((size_t)Hh * Hh * 2);
  f16* w216  = (f16*)alloc((size_t)Hh * Z2 * 2);
  float* cst = (float*)alloc((size_t)Bb * Hh * 4);
  f16* hst   = (f16*)alloc((size_t)Bb * Hh * 2);

  int tc = 2048;
  while (tc > 32) {
    size_t need = (size_t)Bb * tc * G4 * 2 + (size_t)Bb * tc * Hh * 2;
    if (off + need <= ws_size) break;
    tc >>= 1;
  }
  int tcsh = __builtin_ctz((unsigned)tc);
  f16* xp16 = (f16*)alloc((size_t)Bb * tc * G4 * 2);
  f16* h16  = (f16*)alloc((size_t)Bb * tc * Hh * 2);
  f16* hid16 = xp16;  // head hidden aliases xp (xp fully consumed by the scan)

  cast_f16_k<<<(Bb * Tt * Xx) / 1024, 256, 0, stream>>>(x, x16, Bb * Tt * Xx);
  cast_f16_k<<<(Xx * G4) / 1024, 256, 0, stream>>>(Wi, wi16, Xx * G4);
  cast_f16_k<<<(Hh * Hh) / 1024, 256, 0, stream>>>(W1, w116, Hh * Hh);
  cast_f16_k<<<(Hh * Z2) / 1024, 256, 0, stream>>>(W2, w216, Hh * Z2);
  cast_whT_k<<<(Hh * G4) / 256, 256, 0, stream>>>(Wh, whT16);

  float* mu = out;
  float* ls = out + (size_t)Bb * Tt * 64;

  for (int t0 = 0; t0 < Tt; t0 += tc) {
    dim3 gx(Bb * tc / 64, G4 / 64);
    gemm_f16_k<<<gx, 256, 0, stream>>>(x16, wi16, bh, xp16, nullptr, nullptr,
                                       G4, Xx, tcsh, Tt, t0, 0, 0, 0);
    lstm_rec_k<<<Bb, 512, 0, stream>>>(whT16, xp16, h16, cst, hst, tc, (t0 == 0) ? 1 : 0);
    dim3 g1g(Bb * tc / 64, Hh / 64);
    gemm_f16_k<<<g1g, 256, 0, stream>>>(h16, w116, b1, hid16, nullptr, nullptr,
                                        Hh, Hh, 30, 0, 0, 1, 0, 0);
    dim3 g2g(Bb * tc / 64, Z2 / 64);
    gemm_f16_k<<<g2g, 256, 0, stream>>>(hid16, w216, b2, nullptr, mu, ls,
                                        Z2, Hh, 30, 0, 0, 2, t0, tcsh);
  }
}

// Round 3
// 4353.697 us; speedup vs baseline: 3.8063x; 3.6747x over previous
//
#include <hip/hip_runtime.h>

typedef _Float16 f16;
typedef _Float16 h2 __attribute__((ext_vector_type(2)));
typedef _Float16 h8 __attribute__((ext_vector_type(8)));
typedef float f4 __attribute__((ext_vector_type(4)));

constexpr int Bb = 64, Tt = 2048, Xx = 128, Hh = 256, G4 = 1024, Z2 = 128;

__device__ __forceinline__ float fdot2f(h2 a, h2 b, float c) {
#if __has_builtin(__builtin_amdgcn_fdot2)
  return __builtin_amdgcn_fdot2(a, b, c, false);
#else
  return c + (float)a[0] * (float)b[0] + (float)a[1] * (float)b[1];
#endif
}
__device__ __forceinline__ float sigmf(float x) {
  float e = __expf(-x);
  return __builtin_amdgcn_rcpf(1.0f + e);
}
__device__ __forceinline__ float tanhf_(float x) {
  float e = __expf(2.0f * x);
  return 1.0f - 2.0f * __builtin_amdgcn_rcpf(e + 1.0f);
}
__device__ __forceinline__ h2 bch2(unsigned int u) { return __builtin_bit_cast(h2, u); }

// ---------------- casts ----------------
__global__ void cast_f16_k(const float* __restrict__ in, f16* __restrict__ out, int n) {
  int i = (blockIdx.x * 256 + threadIdx.x) * 4;
  if (i >= n) return;
  float4 v = *(const float4*)(in + i);
  h2 a = {(f16)v.x, (f16)v.y};
  h2 b = {(f16)v.z, (f16)v.w};
  uint2 o = {__builtin_bit_cast(unsigned int, a), __builtin_bit_cast(unsigned int, b)};
  *(uint2*)(out + i) = o;
}

// Wh (H=256, 4H=1024) fp32 -> WhT (1024, 256) f16, writes coalesced
__global__ void cast_whT_k(const float* __restrict__ Wh, f16* __restrict__ WhT) {
  int idx = blockIdx.x * 256 + threadIdx.x;  // 262144 = G4*Hh, WhT-linear
  int g = idx >> 8, k = idx & 255;
  WhT[idx] = (f16)Wh[(long)k * G4 + g];
}

// ---------------- generic f16 MFMA GEMM, 64x64 tile ----------------
__global__ __launch_bounds__(256, 4) void gemm_f16_k(
    const f16* __restrict__ A, const f16* __restrict__ Bm, const float* __restrict__ bias,
    f16* __restrict__ C16, float* __restrict__ Cmu, float* __restrict__ Cls,
    int N, int K, int a_shift, int a_ostride, int a_t0,
    int mode, int o_t0, int tcshift)
{
  __shared__ __align__(16) f16 At[64][48];
  __shared__ __align__(16) f16 Bt[64][48];
  const int tid = threadIdx.x;
  const int mblk = blockIdx.x, nblk = blockIdx.y;
  const int w = tid >> 6, lane = tid & 63;

  const int sa_row = tid >> 2, sa_k = (tid & 3) * 8;
  const int m_g = mblk * 64 + sa_row;
  const long arow = (long)(m_g >> a_shift) * a_ostride + a_t0 + (m_g & ((1 << a_shift) - 1));
  const f16* aptr = A + arow * K + sa_k;
  const int sb_k = tid >> 3, sb_n = (tid & 7) * 8;
  const f16* bptr = Bm + (long)sb_k * N + nblk * 64 + sb_n;

  f4 acc[4];
#pragma unroll
  for (int i = 0; i < 4; ++i) acc[i] = (f4){0.f, 0.f, 0.f, 0.f};

  const int arow_l = w * 16 + (lane & 15);
  const int k0 = (lane >> 4) * 8;

  for (int kk = 0; kk < K; kk += 32) {
    uint4 av = *(const uint4*)(aptr + kk);
    uint4 bv = *(const uint4*)(bptr + (long)kk * N);
    __syncthreads();
    *(uint4*)&At[sa_row][sa_k] = av;
    h8 bx = __builtin_bit_cast(h8, bv);
#pragma unroll
    for (int j = 0; j < 8; ++j) Bt[sb_n + j][sb_k] = bx[j];
    __syncthreads();
    h8 af = *(const h8*)&At[arow_l][k0];
#pragma unroll
    for (int nt = 0; nt < 4; ++nt) {
      h8 bf = *(const h8*)&Bt[nt * 16 + (lane & 15)][k0];
      acc[nt] = __builtin_amdgcn_mfma_f32_16x16x32_f16(af, bf, acc[nt], 0, 0, 0);
    }
  }

  const int row_l = w * 16 + ((lane >> 4) << 2);
  const int col_l = lane & 15;
#pragma unroll
  for (int nt = 0; nt < 4; ++nt) {
    int gcol = nblk * 64 + nt * 16 + col_l;
    float bv = bias[gcol];
#pragma unroll
    for (int r = 0; r < 4; ++r) {
      int gm = mblk * 64 + row_l + r;
      float val = acc[nt][r] + bv;
      if (mode == 1) val = fmaxf(val, 0.f);
      if (mode <= 1) {
        C16[(long)gm * N + gcol] = (f16)val;
      } else {
        int bb = gm >> tcshift, tl = gm & ((1 << tcshift) - 1);
        long orow = (long)bb * Tt + o_t0 + tl;
        if (gcol < 64) Cmu[orow * 64 + gcol] = val;
        else Cls[orow * 64 + (gcol - 64)] = val;
      }
    }
  }
}

// ---------------- persistent-weight LSTM scan (one gate column / thread) ----
// 1024 threads/block = 16 waves = 4 waves/EU: the register allocator's natural
// 128-VGPR operating point (rounds 1-2: asking for >128 VGPRs of weights got
// spilled to scratch -> 8 us/step, latency-bound). Per-thread persistent state
// is now 96 weight h2 regs (k<192); k in [192,256) lives in a 128 KB LDS tail.
// Thread tid owns gate column tid of 1024 [i|f|g|o] gates:
//   tid<256: i_j (j=tid) | 256..511: f_j | 512..767: g_j | 768..1023: o_j + c_j
__global__ void __launch_bounds__(1024) __attribute__((amdgpu_waves_per_eu(4, 4)))
lstm_rec_k(
    const f16* __restrict__ WhT, const f16* __restrict__ xp,
    f16* __restrict__ hout, float* __restrict__ c_state, f16* __restrict__ h_state,
    int TC, int first)
{
  const int b = blockIdx.x, tid = threadIdx.x;
  __shared__ __align__(16) h2 hbuf[128];     // h_t as 128 f16 pairs (512 B)
  __shared__ float pbuf[1024];               // activated gates (4 KB)
  __shared__ h2 wlds[16][1024][2];           // weight tail k in [192,256): 128 KB

  h2 w[96];
  {
    const h2* p = (const h2*)(WhT + (long)tid * Hh);
    const uint4* p4 = (const uint4*)p;
#pragma unroll
    for (int i = 0; i < 24; ++i) {
      uint4 v = p4[i];
      w[4 * i + 0] = bch2(v.x); w[4 * i + 1] = bch2(v.y);
      w[4 * i + 2] = bch2(v.z); w[4 * i + 3] = bch2(v.w);
    }
#pragma unroll
    for (int kk = 0; kk < 16; ++kk) {
      wlds[kk][tid][0] = p[96 + 2 * kk];
      wlds[kk][tid][1] = p[97 + 2 * kk];
    }
  }

  float c = 0.f;
  if (tid >= 768 && !first) c = c_state[b * Hh + (tid - 768)];
  if (tid < 128) {
    h2 hz = {(f16)0.f, (f16)0.f};
    hbuf[tid] = first ? hz : ((const h2*)h_state)[b * 128 + tid];
  }
  __syncthreads();

  const f16* xprow = xp + (long)b * TC * G4;
  f16 xc = xprow[tid];
  for (int t = 0; t < TC; ++t) {
    int tn = (t + 1 < TC) ? t + 1 : t;
    f16 xn = xprow[(long)tn * G4 + tid];   // prefetch next step's x-projection

    float acc0 = (float)xc, acc1 = 0.f;    // bh folded into xp already
    const uint4* hb4 = (const uint4*)hbuf;
#pragma unroll
    for (int i = 0; i < 24; ++i) {
      uint4 hv = hb4[i];
      acc0 = fdot2f(w[4 * i + 0], bch2(hv.x), acc0);
      acc1 = fdot2f(w[4 * i + 1], bch2(hv.y), acc1);
      acc0 = fdot2f(w[4 * i + 2], bch2(hv.z), acc0);
      acc1 = fdot2f(w[4 * i + 3], bch2(hv.w), acc1);
    }
#pragma unroll
    for (int kk = 0; kk < 16; ++kk) {
      uint2 wv = *(const uint2*)&wlds[kk][tid][0];
      uint2 hp = *(const uint2*)&hbuf[96 + 2 * kk];
      acc0 = fdot2f(bch2(wv.x), bch2(hp.x), acc0);
      acc1 = fdot2f(bch2(wv.y), bch2(hp.y), acc1);
    }
    float a = acc0 + acc1;

    float act = (tid < 512 || tid >= 768) ? sigmf(a) : tanhf_(a);
    pbuf[tid] = act;
    __syncthreads();
    if (tid >= 768) {
      int j = tid - 768;
      c = pbuf[256 + j] * c + pbuf[j] * pbuf[512 + j];   // f*c + i*tanh(g)
      float hval = act * tanhf_(c);                      // o * tanh(c)
      f16 hh = (f16)hval;
      ((f16*)hbuf)[j] = hh;
      hout[((long)b * TC + t) * Hh + j] = hh;
    }
    __syncthreads();
    xc = xn;
  }
  if (tid >= 768) c_state[b * Hh + (tid - 768)] = c;
  if (tid < 128) ((h2*)h_state)[b * 128 + tid] = hbuf[tid];
}

// ---------------- host ----------------
extern "C" void kernel_launch(void* const* d_in, const int* in_sizes, int n_in,
                              void* d_out, int out_size, void* d_ws, size_t ws_size,
                              hipStream_t stream)
{
  const float* x  = (const float*)d_in[0];
  const float* Wi = (const float*)d_in[1];
  const float* Wh = (const float*)d_in[2];
  const float* bh = (const float*)d_in[3];
  const float* W1 = (const float*)d_in[4];
  const float* b1 = (const float*)d_in[5];
  const float* W2 = (const float*)d_in[6];
  const float* b2 = (const float*)d_in[7];
  float* out = (float*)d_out;

  char* ws = (char*)d_ws;
  size_t off = 0;
  auto alloc = [&](size_t bytes) -> char* {
    char* p = ws + off;
    off = (off + bytes + 255) & ~(size_t)255;
    return p;
  };
  f16* x16   = (f16*)alloc((size_t)Bb * Tt * Xx * 2);
  f16* wi16  = (f16*)alloc((size_t)Xx * G4 * 2);
  f16* whT16 = (f16*)alloc((size_t)G4 * Hh * 2);
  f16* w116  = (f16*)alloc((size_t)Hh * Hh * 2);
  f16* w216  = (f16*)alloc((size_t)Hh * Z2 * 2);
  float* cst = (float*)alloc((size_t)Bb * Hh * 4);
  f16* hst   = (f16*)alloc((size_t)Bb * Hh * 2);

  int tc = 2048;
  while (tc > 32) {
    size_t need = (size_t)Bb * tc * G4 * 2 + (size_t)Bb * tc * Hh * 2;
    if (off + need <= ws_size) break;
    tc >>= 1;
  }
  int tcsh = __builtin_ctz((unsigned)tc);
  f16* xp16 = (f16*)alloc((size_t)Bb * tc * G4 * 2);
  f16* h16  = (f16*)alloc((size_t)Bb * tc * Hh * 2);
  f16* hid16 = xp16;  // head hidden aliases xp (xp fully consumed by the scan)

  cast_f16_k<<<(Bb * Tt * Xx) / 1024, 256, 0, stream>>>(x, x16, Bb * Tt * Xx);
  cast_f16_k<<<(Xx * G4) / 1024, 256, 0, stream>>>(Wi, wi16, Xx * G4);
  cast_f16_k<<<(Hh * Hh) / 1024, 256, 0, stream>>>(W1, w116, Hh * Hh);
  cast_f16_k<<<(Hh * Z2) / 1024, 256, 0, stream>>>(W2, w216, Hh * Z2);
  cast_whT_k<<<(Hh * G4) / 256, 256, 0, stream>>>(Wh, whT16);

  float* mu = out;
  float* ls = out + (size_t)Bb * Tt * 64;

  for (int t0 = 0; t0 < Tt; t0 += tc) {
    dim3 gx(Bb * tc / 64, G4 / 64);
    gemm_f16_k<<<gx, 256, 0, stream>>>(x16, wi16, bh, xp16, nullptr, nullptr,
                                       G4, Xx, tcsh, Tt, t0, 0, 0, 0);
    lstm_rec_k<<<Bb, 1024, 0, stream>>>(whT16, xp16, h16, cst, hst, tc, (t0 == 0) ? 1 : 0);
    dim3 g1g(Bb * tc / 64, Hh / 64);
    gemm_f16_k<<<g1g, 256, 0, stream>>>(h16, w116, b1, hid16, nullptr, nullptr,
                                        Hh, Hh, 30, 0, 0, 1, 0, 0);
    dim3 g2g(Bb * tc / 64, Z2 / 64);
    gemm_f16_k<<<g2g, 256, 0, stream>>>(hid16, w216, b2, nullptr, mu, ls,
                                        Z2, Hh, 30, 0, 0, 2, t0, tcsh);
  }
}